// Round 1
// baseline (212.930 us; speedup 1.0000x reference)
//
#include <hip/hip_runtime.h>

// Correlation: out[b,(p+4)*9+(q+4),y,x] = (1/128) * sum_c A[b,c,y,x]*B[b,c,y+p,x+q]
// A,B = (8,128,128,128) fp32; out = (8,81,128,128) fp32. B zero-padded.
//
// R6: barrier-drain fix. __syncthreads() lowers to s_waitcnt vmcnt(0) before
// s_barrier, draining the just-issued prefetch loads every chunk -> full global
// latency exposed 32x per block (VALUBusy 27.5%, both pipes idle). Replace with
// raw s_barrier + lgkmcnt(0)-only wait (LDS is the only cross-wave state), so
// global loads stay in flight across barriers; deepen register prefetch to 2
// chunk-sets (load 3 chunks ahead, ~2 iterations of slack). Chunk c lives in
// register-set/LDS-buffer (c&1); all set indices are macro-literal so the sets
// stay in VGPRs. Keeps R4/R5 structure: f16 pair-packing + v_dot2_f32_f16,
// 192-thread blocks (3 waves), grid 3072, LDS 10.75 KB.

typedef __fp16 h2 __attribute__((ext_vector_type(2)));

#define BW2 144   // padded B row in h2 units; j = x+4, valid j in [0,136), pad to 144

#if __has_builtin(__builtin_amdgcn_fdot2)
  #define FDOT2(a, b, c) __builtin_amdgcn_fdot2((a), (b), (c), false)
#else
  static __device__ inline float FDOT2(h2 a, h2 b, float c) {
      return c + (float)a.x * (float)b.x + (float)a.y * (float)b.y;
  }
#endif

static __device__ inline float pk2f(float lo, float hi) {
    h2 v = __builtin_amdgcn_cvt_pkrtz(lo, hi);   // (f16(lo), f16(hi)) packed
    return __builtin_bit_cast(float, v);
}
static __device__ inline h2 f2h2(float f) { return __builtin_bit_cast(h2, f); }

// Raw barrier: lgkmcnt(0) guarantees our ds_writes are committed (and our
// ds_reads done) before the rendezvous; NO vmcnt wait, so prefetch global
// loads stay outstanding across the barrier. "memory" clobbers pin LDS ops
// on the correct side.
#define BARRIER() do {                                    \
    asm volatile("" ::: "memory");                        \
    asm volatile("s_waitcnt lgkmcnt(0)" ::: "memory");    \
    __builtin_amdgcn_s_barrier();                         \
    asm volatile("" ::: "memory");                        \
} while (0)

__global__ __launch_bounds__(192, 4)
void corr_kernel(const float* __restrict__ A, const float* __restrict__ B,
                 float* __restrict__ out)
{
    const int bidx = blockIdx.x;
    const int bb = bidx & 7;          // batch -> XCD affinity
    const int t2 = bidx >> 3;
    const int y  = t2 & 127;
    const int pg = t2 >> 7;           // p-group 0..2

    const int tid  = threadIdx.x;     // 0..191
    const int wave = tid >> 6;        // 0..2
    const int lane = tid & 63;
    const int cs   = lane >> 5;       // pair-select within 4-channel chunk
    const int x0   = (lane & 31) << 2;
    const int pr   = pg * 3 + wave;   // 0..8 -> p = pr-4

    __shared__ h2 a_s[2][2][128];     // [buf][pair][x]
    __shared__ h2 b_s[2][3][2][BW2];  // [buf][row-slot][pair][j]

    float acc[9][4];
    #pragma unroll
    for (int q = 0; q < 9; ++q)
        #pragma unroll
        for (int i = 0; i < 4; ++i) acc[q][i] = 0.f;

    const long plane = 128L * 128L;
    const float* Abase = A + (long)bb * 128 * plane + (long)y * 128;
    const float* Bbase = B + (long)bb * 128 * plane;

    // B staging map: 6 row-pairs (3 row-slots x 2 pairs) x 32 threads, 1 packed f4/thread
    const int i4  = (tid & 31) << 2;     // float column
    const int rp  = tid >> 5;            // 0..5
    const int brw = rp >> 1;             // row slot 0..2
    const int bpp = rp & 1;              // pair 0/1
    const int bys = y + pg * 3 + brw - 4;
    const bool bval = (unsigned)bys < 128u;
    const float* Bsrc = Bbase + (long)bys * 128 + i4;   // + c*plane per chunk

    // A staging map: threads < 64: 2 pairs x 32 columns
    const bool aact = tid < 64;
    const int app = (tid >> 5) & 1;

    // Two register chunk-sets: chunk c -> set (c&1) -> LDS buffer (c&1).
    float4 rb0[2], rb1[2], ra0[2], ra1[2];

#define LOADC(CHUNK, S) do {                                             \
    const int ch0_ = (CHUNK) << 2;                                       \
    if (bval) {                                                          \
        const int c0_ = ch0_ + (bpp << 1);                               \
        rb0[(S)] = *(const float4*)(Bsrc + (long)c0_ * plane);           \
        rb1[(S)] = *(const float4*)(Bsrc + (long)(c0_ + 1) * plane);     \
    }                                                                    \
    if (aact) {                                                          \
        const int c0_ = ch0_ + (app << 1);                               \
        ra0[(S)] = *(const float4*)(Abase + (long)c0_ * plane + i4);     \
        ra1[(S)] = *(const float4*)(Abase + (long)(c0_ + 1) * plane + i4);\
    }                                                                    \
} while (0)

#define STAGE(S) do {                                                    \
    if (bval) {                                                          \
        float4 w_;                                                       \
        w_.x = pk2f(rb0[(S)].x, rb1[(S)].x);                             \
        w_.y = pk2f(rb0[(S)].y, rb1[(S)].y);                             \
        w_.z = pk2f(rb0[(S)].z, rb1[(S)].z);                             \
        w_.w = pk2f(rb0[(S)].w, rb1[(S)].w);                             \
        *(float4*)&b_s[(S)][brw][bpp][4 + i4] = w_;   /* j = 4 + x */    \
    }                                                                    \
    if (aact) {                                                          \
        float4 w_;                                                       \
        w_.x = pk2f(ra0[(S)].x, ra1[(S)].x);                             \
        w_.y = pk2f(ra0[(S)].y, ra1[(S)].y);                             \
        w_.z = pk2f(ra0[(S)].z, ra1[(S)].z);                             \
        w_.w = pk2f(ra0[(S)].w, ra1[(S)].w);                             \
        *(float4*)&a_s[(S)][app][i4] = w_;                               \
    }                                                                    \
} while (0)

// body(K): compute chunk K from buf S(=K&1); stage chunk K+1 (regs set S^1,
// loaded 2 bodies ago -> counted vmcnt by compiler); issue loads for chunk
// K+3 into set S^1; raw barrier (loads stay in flight).
#define BODY(K, S) do {                                                          \
    {                                                                            \
        const float4 av  = *(const float4*)&a_s[(S)][cs][x0];                    \
        const float4 b0v = *(const float4*)&b_s[(S)][wave][cs][x0];              \
        const float4 b1v = *(const float4*)&b_s[(S)][wave][cs][x0 + 4];          \
        const float4 b2v = *(const float4*)&b_s[(S)][wave][cs][x0 + 8];          \
        const h2 a2[4] = { f2h2(av.x), f2h2(av.y), f2h2(av.z), f2h2(av.w) };     \
        const h2 w[12] = { f2h2(b0v.x), f2h2(b0v.y), f2h2(b0v.z), f2h2(b0v.w),   \
                           f2h2(b1v.x), f2h2(b1v.y), f2h2(b1v.z), f2h2(b1v.w),   \
                           f2h2(b2v.x), f2h2(b2v.y), f2h2(b2v.z), f2h2(b2v.w) }; \
        _Pragma("unroll")                                                        \
        for (int q = 0; q < 9; ++q)                                              \
            _Pragma("unroll")                                                    \
            for (int i = 0; i < 4; ++i)                                          \
                acc[q][i] = FDOT2(a2[i], w[q + i], acc[q][i]);                   \
    }                                                                            \
    if ((K) + 1 < 32) STAGE((S) ^ 1);                                            \
    if ((K) + 3 < 32) LOADC((K) + 3, (S) ^ 1);                                   \
    BARRIER();                                                                   \
} while (0)

    // Prologue: issue chunk0/chunk1 loads first so their latency overlaps the
    // LDS zero-init; then zero pads, barrier, stage chunk0, issue chunk2.
    LOADC(0, 0);
    LOADC(1, 1);

    {   // one-time zero: pads (j<4, j>=136) and OOB rows stay zero forever
        float4* pa = (float4*)&a_s[0][0][0];
        const int na = 2 * 2 * 128 / 4;       // 128 float4
        for (int i = tid; i < na; i += 192) pa[i] = make_float4(0.f, 0.f, 0.f, 0.f);
        float4* pb = (float4*)&b_s[0][0][0][0];
        const int nb = 2 * 3 * 2 * BW2 / 4;   // 432 float4
        for (int i = tid; i < nb; i += 192) pb[i] = make_float4(0.f, 0.f, 0.f, 0.f);
    }
    BARRIER();          // zero-init visible before first stage writes
    STAGE(0);
    LOADC(2, 0);
    BARRIER();          // buf0 ready; chunk1/chunk2 loads still in flight

    for (int k = 0; k < 32; k += 2) {
        BODY(k, 0);
        BODY(k + 1, 1);
    }

#undef BODY
#undef STAGE
#undef LOADC

    // combine pair-split halves (lane L += lane L+32)
    #pragma unroll
    for (int q = 0; q < 9; ++q)
        #pragma unroll
        for (int i = 0; i < 4; ++i)
            acc[q][i] += __shfl_down(acc[q][i], 32);

    if (cs == 0) {
        const float scale = 1.0f / 128.0f;
        float* obase = out + (((long)bb * 81 + (long)pr * 9) * 128 + y) * 128 + x0;
        #pragma unroll
        for (int q = 0; q < 9; ++q) {
            const float4 v = make_float4(acc[q][0] * scale, acc[q][1] * scale,
                                         acc[q][2] * scale, acc[q][3] * scale);
            *(float4*)(obase + (long)q * plane) = v;
        }
    }
}

extern "C" void kernel_launch(void* const* d_in, const int* in_sizes, int n_in,
                              void* d_out, int out_size, void* d_ws, size_t ws_size,
                              hipStream_t stream) {
    const float* a = (const float*)d_in[0];
    const float* b = (const float*)d_in[1];
    float* out = (float*)d_out;
    // grid: 8 batches * 128 y * 3 p-groups = 3072 blocks; 192 threads (3 waves)
    hipLaunchKernelGGL(corr_kernel, dim3(3072), dim3(192), 0, stream, a, b, out);
}